// Round 1
// baseline (356.860 us; speedup 1.0000x reference)
//
#include <hip/hip_runtime.h>
#include <hip/hip_bf16.h>
#include <math.h>

#define Bsz 8
#define Nseq 512
#define Emb 256
#define Hn 8
#define DKc 32
#define NEGV -1e10f

// ---------------------------------------------------------------------------
// Generic fp32 GEMM: C = act(A(MxK) @ B(KxN) + bias). Row-major, lda=K, ldb=ldc=N.
// 64x64 tile, 256 threads, 4x4 per thread, k-step 16. All dims multiples of 64/16.
// ---------------------------------------------------------------------------
template<int RELU, int HASBIAS>
__global__ __launch_bounds__(256) void gemm_k(const float* __restrict__ A,
                                              const float* __restrict__ Bm,
                                              const float* __restrict__ bias,
                                              float* __restrict__ C,
                                              int M, int Nn, int K)
{
    __shared__ float As[16][68];   // stride 68: float4-aligned, conflict-benign
    __shared__ float Bs[16][68];
    const int tid = threadIdx.x;
    const int tx = tid & 15, ty = tid >> 4;
    const int row0 = blockIdx.x * 64, col0 = blockIdx.y * 64;
    const int mA = tid >> 2, kqA = (tid & 3) << 2;       // A tile: 64 rows x 16 k
    const int kkB = tid >> 4, nqB = (tid & 15) << 2;     // B tile: 16 k x 64 cols
    float c[4][4] = {};

    for (int k0 = 0; k0 < K; k0 += 16) {
        __syncthreads();
        float4 a4 = *(const float4*)(A + (size_t)(row0 + mA) * K + k0 + kqA);
        As[kqA + 0][mA] = a4.x; As[kqA + 1][mA] = a4.y;
        As[kqA + 2][mA] = a4.z; As[kqA + 3][mA] = a4.w;
        *(float4*)&Bs[kkB][nqB] =
            *(const float4*)(Bm + (size_t)(k0 + kkB) * Nn + col0 + nqB);
        __syncthreads();
        #pragma unroll
        for (int kk = 0; kk < 16; ++kk) {
            float4 av = *(const float4*)&As[kk][ty << 2];
            float4 bv = *(const float4*)&Bs[kk][tx << 2];
            const float aa[4] = {av.x, av.y, av.z, av.w};
            const float bb[4] = {bv.x, bv.y, bv.z, bv.w};
            #pragma unroll
            for (int i = 0; i < 4; ++i)
                #pragma unroll
                for (int jj = 0; jj < 4; ++jj)
                    c[i][jj] = fmaf(aa[i], bb[jj], c[i][jj]);
        }
    }

    float bvv[4] = {0.f, 0.f, 0.f, 0.f};
    if (HASBIAS) {
        #pragma unroll
        for (int jj = 0; jj < 4; ++jj) bvv[jj] = bias[col0 + (tx << 2) + jj];
    }
    #pragma unroll
    for (int i = 0; i < 4; ++i) {
        const int rr = row0 + (ty << 2) + i;
        float4 o;
        o.x = c[i][0] + bvv[0]; o.y = c[i][1] + bvv[1];
        o.z = c[i][2] + bvv[2]; o.w = c[i][3] + bvv[3];
        if (RELU) {
            o.x = fmaxf(o.x, 0.f); o.y = fmaxf(o.y, 0.f);
            o.z = fmaxf(o.z, 0.f); o.w = fmaxf(o.w, 0.f);
        }
        *(float4*)(C + (size_t)rr * Nn + col0 + (tx << 2)) = o;
    }
}

// ---------------------------------------------------------------------------
// bcomb[j] = bs1[j] + sum_{r=0..767} bo[r&255] * Ws1[r][j]   (bcomb pre-zeroed)
// ---------------------------------------------------------------------------
__global__ void bcomb_k(const float* __restrict__ bo, const float* __restrict__ Ws1,
                        const float* __restrict__ bs1, float* __restrict__ bcomb)
{
    const int jj = threadIdx.x;            // 256
    const int r0 = blockIdx.x * 64;        // grid 12
    float acc = (blockIdx.x == 0) ? bs1[jj] : 0.f;
    for (int r = r0; r < r0 + 64; ++r)
        acc = fmaf(bo[r & 255], Ws1[(size_t)r * Emb + jj], acc);
    atomicAdd(&bcomb[jj], acc);
}

// ---------------------------------------------------------------------------
// Flash-style 3-scale attention. Block = one (b,h) x 64 q-rows, 256 threads.
// thread t: q-row r = t>>2, k-quarter j = t&3 (16 k's per thread per 64-chunk).
// K/V rows stored at permuted LDS slot (row&15)*4+(row>>4) so the 4 j-lanes hit
// 4 distinct bank groups in the hot b128 loops (naive layout = 4-way conflict).
// Writes o_s (pre-Wo) into OB[b][n][s*256 + h*32 + d].
// ---------------------------------------------------------------------------
__global__ __launch_bounds__(256, 2) void attn_k(
    const float* __restrict__ qg, const float* __restrict__ kg,
    const float* __restrict__ vg, const float* __restrict__ dist,
    const int* __restrict__ mask,
    const float* __restrict__ cw1, const float* __restrict__ cb1,
    const float* __restrict__ cw2, const float* __restrict__ cb2,
    float* __restrict__ OB)
{
    const int bh = blockIdx.x;             // 64 = B*H
    const int b = bh >> 3, h = bh & 7;
    const int q0 = blockIdx.y * 64;
    const int t = threadIdx.x;
    const int r = t >> 2;                  // q row within tile
    const int j = t & 3;                   // k quarter

    __shared__ float Qs[64][36];
    __shared__ float Ks[64][36];
    __shared__ float Vs[64][36];

    // distance-conv params (uniform -> scalar regs)
    float w1[8], b1[8], w2[8];
    #pragma unroll
    for (int i = 0; i < 8; ++i) { w1[i] = cw1[i]; b1[i] = cb1[i]; w2[i] = cw2[h * 8 + i]; }
    const float c2b = cb2[h];
    const float inv_sqrt = 0.17677669529663687f;   // 1/sqrt(32)

    // stage Q tile (coalesced), then cache own row in regs
    {
        const int row = t >> 2, cq = (t & 3) << 3;
        const float* src = qg + (size_t)(b * Nseq + q0 + row) * Emb + h * DKc + cq;
        *(float4*)&Qs[row][cq]     = *(const float4*)src;
        *(float4*)&Qs[row][cq + 4] = *(const float4*)(src + 4);
    }
    __syncthreads();
    float qreg[32];
    #pragma unroll
    for (int c4 = 0; c4 < 32; c4 += 4) {
        float4 x = *(const float4*)&Qs[r][c4];
        qreg[c4] = x.x; qreg[c4 + 1] = x.y; qreg[c4 + 2] = x.z; qreg[c4 + 3] = x.w;
    }

    float m[3] = {-INFINITY, -INFINITY, -INFINITY};
    float l[3] = {0.f, 0.f, 0.f};
    float acc[3][32] = {};
    const float bars[3] = {0.3f, 0.7f, 1e10f};
    const size_t dm_base = ((size_t)b * Nseq + (q0 + r)) * Nseq;
    const bool qz = (q0 + r) == 0;
    const int srow = t >> 3, scq = (t & 7) << 2;   // staging map

    for (int kc = 0; kc < 8; ++kc) {
        const int kk0 = kc * 64;
        __syncthreads();
        #pragma unroll
        for (int half = 0; half < 2; ++half) {
            const int rr = srow + half * 32;
            const int slot = ((rr & 15) << 2) | (rr >> 4);
            const size_t g = (size_t)(b * Nseq + kk0 + rr) * Emb + h * DKc + scq;
            *(float4*)&Ks[slot][scq] = *(const float4*)(kg + g);
            *(float4*)&Vs[slot][scq] = *(const float4*)(vg + g);
        }
        __syncthreads();

        // dist / mask for my 16 columns
        float dd[16]; int mk[16];
        #pragma unroll
        for (int g4 = 0; g4 < 4; ++g4) {
            float4 dv = *(const float4*)&dist[dm_base + kk0 + (j << 4) + g4 * 4];
            dd[g4 * 4 + 0] = dv.x; dd[g4 * 4 + 1] = dv.y;
            dd[g4 * 4 + 2] = dv.z; dd[g4 * 4 + 3] = dv.w;
            int4 mv = *(const int4*)&mask[dm_base + kk0 + (j << 4) + g4 * 4];
            mk[g4 * 4 + 0] = mv.x; mk[g4 * 4 + 1] = mv.y;
            mk[g4 * 4 + 2] = mv.z; mk[g4 * 4 + 3] = mv.w;
        }

        // scores (QK^T * f_h(d), mask applied)
        float sc[16];
        #pragma unroll
        for (int i = 0; i < 16; ++i) {
            const int slot = (i << 2) | j;         // perm of krow = j*16+i
            float dot = 0.f;
            #pragma unroll
            for (int c4 = 0; c4 < 32; c4 += 4) {
                float4 kv = *(const float4*)&Ks[slot][c4];
                dot = fmaf(qreg[c4], kv.x, dot);
                dot = fmaf(qreg[c4 + 1], kv.y, dot);
                dot = fmaf(qreg[c4 + 2], kv.z, dot);
                dot = fmaf(qreg[c4 + 3], kv.w, dot);
            }
            const float d = dd[i];
            float f = c2b;
            #pragma unroll
            for (int u = 0; u < 8; ++u)
                f = fmaf(w2[u], fmaxf(fmaf(d, w1[u], b1[u]), 0.f), f);
            float s = dot * inv_sqrt * f;
            sc[i] = (mk[i] == 0) ? NEGV : s;
        }

        // online-softmax state update per scale
        const int kglob0 = kk0 + (j << 4);
        float mn[3];
        #pragma unroll
        for (int sI = 0; sI < 3; ++sI) {
            float cm = -INFINITY;
            #pragma unroll
            for (int i = 0; i < 16; ++i) {
                const bool dm = qz || (kglob0 + i == 0) || (dd[i] < bars[sI]);
                cm = fmaxf(cm, dm ? sc[i] : NEGV);
            }
            cm = fmaxf(cm, __shfl_xor(cm, 1));
            cm = fmaxf(cm, __shfl_xor(cm, 2));
            const float mnew = fmaxf(m[sI], cm);
            const float alpha = __expf(m[sI] - mnew);
            m[sI] = mnew; mn[sI] = mnew;
            l[sI] *= alpha;
            #pragma unroll
            for (int d4 = 0; d4 < 32; ++d4) acc[sI][d4] *= alpha;
        }

        // P·V, sharing each V read across the 3 scales
        #pragma unroll
        for (int i = 0; i < 16; ++i) {
            const bool k0f = qz || (kglob0 + i == 0);
            const float s = sc[i], d = dd[i];
            const float p0 = __expf(((k0f || d < 0.3f) ? s : NEGV) - mn[0]);
            const float p1 = __expf(((k0f || d < 0.7f) ? s : NEGV) - mn[1]);
            const float p2 = __expf(s - mn[2]);    // bar=1e10: always in range
            l[0] += p0; l[1] += p1; l[2] += p2;
            const int slot = (i << 2) | j;
            #pragma unroll
            for (int d4 = 0; d4 < 32; d4 += 4) {
                float4 v4 = *(const float4*)&Vs[slot][d4];
                acc[0][d4 + 0] = fmaf(p0, v4.x, acc[0][d4 + 0]);
                acc[0][d4 + 1] = fmaf(p0, v4.y, acc[0][d4 + 1]);
                acc[0][d4 + 2] = fmaf(p0, v4.z, acc[0][d4 + 2]);
                acc[0][d4 + 3] = fmaf(p0, v4.w, acc[0][d4 + 3]);
                acc[1][d4 + 0] = fmaf(p1, v4.x, acc[1][d4 + 0]);
                acc[1][d4 + 1] = fmaf(p1, v4.y, acc[1][d4 + 1]);
                acc[1][d4 + 2] = fmaf(p1, v4.z, acc[1][d4 + 2]);
                acc[1][d4 + 3] = fmaf(p1, v4.w, acc[1][d4 + 3]);
                acc[2][d4 + 0] = fmaf(p2, v4.x, acc[2][d4 + 0]);
                acc[2][d4 + 1] = fmaf(p2, v4.y, acc[2][d4 + 1]);
                acc[2][d4 + 2] = fmaf(p2, v4.z, acc[2][d4 + 2]);
                acc[2][d4 + 3] = fmaf(p2, v4.w, acc[2][d4 + 3]);
            }
        }
    }

    // cross-quad reduce + write o_s into OB[b][n][s*256 + h*32 + d]
    #pragma unroll
    for (int sI = 0; sI < 3; ++sI) {
        float lt = l[sI];
        lt += __shfl_xor(lt, 1);
        lt += __shfl_xor(lt, 2);
        const float inv_l = 1.0f / lt;
        float ov[8];
        #pragma unroll
        for (int d = 0; d < 32; ++d) {
            float v = acc[sI][d];
            v += __shfl_xor(v, 1);
            v += __shfl_xor(v, 2);
            if ((d >> 3) == j) ov[d & 7] = v;
        }
        float* op = OB + ((size_t)(b * Nseq + q0 + r)) * 768 + sI * 256 + h * 32 + (j << 3);
        float4 o0 = {ov[0] * inv_l, ov[1] * inv_l, ov[2] * inv_l, ov[3] * inv_l};
        float4 o1 = {ov[4] * inv_l, ov[5] * inv_l, ov[6] * inv_l, ov[7] * inv_l};
        *(float4*)op = o0;
        *(float4*)(op + 4) = o1;
    }
}

// ---------------------------------------------------------------------------
extern "C" void kernel_launch(void* const* d_in, const int* in_sizes, int n_in,
                              void* d_out, int out_size, void* d_ws, size_t ws_size,
                              hipStream_t stream)
{
    const float* query = (const float*)d_in[0];
    const float* key   = (const float*)d_in[1];
    const float* value = (const float*)d_in[2];
    const float* dist  = (const float*)d_in[3];
    const int*   mask  = (const int*)d_in[4];
    const float* Wq = (const float*)d_in[5];  const float* bq = (const float*)d_in[6];
    const float* Wk = (const float*)d_in[7];  const float* bk = (const float*)d_in[8];
    const float* Wv = (const float*)d_in[9];  const float* bv = (const float*)d_in[10];
    const float* Wo = (const float*)d_in[11]; const float* bo = (const float*)d_in[12];
    const float* cw1 = (const float*)d_in[13]; const float* cb1 = (const float*)d_in[14];
    const float* cw2 = (const float*)d_in[15]; const float* cb2 = (const float*)d_in[16];
    const float* Ws1 = (const float*)d_in[17]; const float* bs1 = (const float*)d_in[18];
    const float* Ws2 = (const float*)d_in[19]; const float* bs2 = (const float*)d_in[20];

    float* ws    = (float*)d_ws;
    float* qb    = ws;                  // 4096x256
    float* kb    = qb + 1048576;        // 4096x256
    float* vb    = kb + 1048576;        // 4096x256
    float* OB    = vb + 1048576;        // 4096x768 (o_s pre-projection, concat layout)
    float* h1    = OB + 3145728;        // 4096x256
    float* Wbig  = h1 + 1048576;        // 768x256 = Wo @ Ws1_s stacked
    float* bcomb = Wbig + 196608;       // 256

    hipMemsetAsync(bcomb, 0, 256 * sizeof(float), stream);
    bcomb_k<<<dim3(12), dim3(256), 0, stream>>>(bo, Ws1, bs1, bcomb);

    gemm_k<0, 1><<<dim3(64, 4), 256, 0, stream>>>(query, Wq, bq, qb, 4096, 256, 256);
    gemm_k<0, 1><<<dim3(64, 4), 256, 0, stream>>>(key,   Wk, bk, kb, 4096, 256, 256);
    gemm_k<0, 1><<<dim3(64, 4), 256, 0, stream>>>(value, Wv, bv, vb, 4096, 256, 256);

    for (int s = 0; s < 3; ++s)
        gemm_k<0, 0><<<dim3(4, 4), 256, 0, stream>>>(Wo, Ws1 + s * 65536, nullptr,
                                                     Wbig + s * 65536, 256, 256, 256);

    attn_k<<<dim3(64, 8), 256, 0, stream>>>(qb, kb, vb, dist, mask,
                                            cw1, cb1, cw2, cb2, OB);

    gemm_k<1, 1><<<dim3(64, 4), 256, 0, stream>>>(OB, Wbig, bcomb, h1, 4096, 256, 768);
    gemm_k<0, 1><<<dim3(64, 4), 256, 0, stream>>>(h1, Ws2, bs2, (float*)d_out,
                                                  4096, 256, 256);
}

// Round 2
// 270.307 us; speedup vs baseline: 1.3202x; 1.3202x over previous
//
#include <hip/hip_runtime.h>
#include <hip/hip_bf16.h>
#include <math.h>

typedef unsigned short ushortT;
typedef unsigned int uintT;
typedef __attribute__((ext_vector_type(8))) short short8;
typedef __attribute__((ext_vector_type(4))) float floatx4;

#define NEGV -1e10f

static __device__ __forceinline__ uintT f2bf_u(float x) {
    uintT u = __float_as_uint(x);
    return (u + 0x7fffu + ((u >> 16) & 1u)) >> 16;
}
static __device__ __forceinline__ ushortT f2bf(float x) { return (ushortT)f2bf_u(x); }

// ---------------------------------------------------------------------------
// Generic fp32 GEMM: C = act(A(MxK) @ B(KxN) + bias), z-batched via bz/cz strides.
// ---------------------------------------------------------------------------
template<int RELU, int HASBIAS>
__global__ __launch_bounds__(256) void gemm_k(const float* __restrict__ A,
                                              const float* __restrict__ Bm,
                                              const float* __restrict__ bias,
                                              float* __restrict__ C,
                                              int M, int Nn, int K,
                                              long bz, long cz)
{
    Bm += (long)blockIdx.z * bz;
    C  += (long)blockIdx.z * cz;
    __shared__ float As[16][68];
    __shared__ float Bs[16][68];
    const int tid = threadIdx.x;
    const int tx = tid & 15, ty = tid >> 4;
    const int row0 = blockIdx.x * 64, col0 = blockIdx.y * 64;
    const int mA = tid >> 2, kqA = (tid & 3) << 2;
    const int kkB = tid >> 4, nqB = (tid & 15) << 2;
    float c[4][4] = {};

    for (int k0 = 0; k0 < K; k0 += 16) {
        __syncthreads();
        float4 a4 = *(const float4*)(A + (size_t)(row0 + mA) * K + k0 + kqA);
        As[kqA + 0][mA] = a4.x; As[kqA + 1][mA] = a4.y;
        As[kqA + 2][mA] = a4.z; As[kqA + 3][mA] = a4.w;
        *(float4*)&Bs[kkB][nqB] =
            *(const float4*)(Bm + (size_t)(k0 + kkB) * Nn + col0 + nqB);
        __syncthreads();
        #pragma unroll
        for (int kk = 0; kk < 16; ++kk) {
            float4 av = *(const float4*)&As[kk][ty << 2];
            float4 bv = *(const float4*)&Bs[kk][tx << 2];
            const float aa[4] = {av.x, av.y, av.z, av.w};
            const float bb[4] = {bv.x, bv.y, bv.z, bv.w};
            #pragma unroll
            for (int i = 0; i < 4; ++i)
                #pragma unroll
                for (int jj = 0; jj < 4; ++jj)
                    c[i][jj] = fmaf(aa[i], bb[jj], c[i][jj]);
        }
    }

    float bvv[4] = {0.f, 0.f, 0.f, 0.f};
    if (HASBIAS) {
        #pragma unroll
        for (int jj = 0; jj < 4; ++jj) bvv[jj] = bias[col0 + (tx << 2) + jj];
    }
    #pragma unroll
    for (int i = 0; i < 4; ++i) {
        const int rr = row0 + (ty << 2) + i;
        float4 o;
        o.x = c[i][0] + bvv[0]; o.y = c[i][1] + bvv[1];
        o.z = c[i][2] + bvv[2]; o.w = c[i][3] + bvv[3];
        if (RELU) {
            o.x = fmaxf(o.x, 0.f); o.y = fmaxf(o.y, 0.f);
            o.z = fmaxf(o.z, 0.f); o.w = fmaxf(o.w, 0.f);
        }
        *(float4*)(C + (size_t)rr * Nn + col0 + (tx << 2)) = o;
    }
}

// ---------------------------------------------------------------------------
// QKV projection, z-batched (z=0:Q, 1:K, 2:V). M=4096, N=256, K=256 fixed.
// Q/K written bf16 row-major; V written bf16 TRANSPOSED per (b,h): vbT[(b*8+h)*32+d][n].
// ---------------------------------------------------------------------------
__global__ __launch_bounds__(256) void qkv_gemm_k(
    const float* __restrict__ Xq, const float* __restrict__ Xk, const float* __restrict__ Xv,
    const float* __restrict__ Wq, const float* __restrict__ bq,
    const float* __restrict__ Wk, const float* __restrict__ bk,
    const float* __restrict__ Wv, const float* __restrict__ bv,
    ushortT* __restrict__ qb, ushortT* __restrict__ kb, ushortT* __restrict__ vbT)
{
    const int z = blockIdx.z;
    const float* A    = (z == 0) ? Xq : (z == 1) ? Xk : Xv;
    const float* Bm   = (z == 0) ? Wq : (z == 1) ? Wk : Wv;
    const float* bias = (z == 0) ? bq : (z == 1) ? bk : bv;

    __shared__ float As[16][68];
    __shared__ float Bs[16][68];
    const int tid = threadIdx.x;
    const int tx = tid & 15, ty = tid >> 4;
    const int row0 = blockIdx.x * 64, col0 = blockIdx.y * 64;
    const int mA = tid >> 2, kqA = (tid & 3) << 2;
    const int kkB = tid >> 4, nqB = (tid & 15) << 2;
    float c[4][4] = {};

    for (int k0 = 0; k0 < 256; k0 += 16) {
        __syncthreads();
        float4 a4 = *(const float4*)(A + (size_t)(row0 + mA) * 256 + k0 + kqA);
        As[kqA + 0][mA] = a4.x; As[kqA + 1][mA] = a4.y;
        As[kqA + 2][mA] = a4.z; As[kqA + 3][mA] = a4.w;
        *(float4*)&Bs[kkB][nqB] =
            *(const float4*)(Bm + (size_t)(k0 + kkB) * 256 + col0 + nqB);
        __syncthreads();
        #pragma unroll
        for (int kk = 0; kk < 16; ++kk) {
            float4 av = *(const float4*)&As[kk][ty << 2];
            float4 bv4 = *(const float4*)&Bs[kk][tx << 2];
            const float aa[4] = {av.x, av.y, av.z, av.w};
            const float bb[4] = {bv4.x, bv4.y, bv4.z, bv4.w};
            #pragma unroll
            for (int i = 0; i < 4; ++i)
                #pragma unroll
                for (int jj = 0; jj < 4; ++jj)
                    c[i][jj] = fmaf(aa[i], bb[jj], c[i][jj]);
        }
    }

    float bvv[4];
    #pragma unroll
    for (int jj = 0; jj < 4; ++jj) bvv[jj] = bias[col0 + (tx << 2) + jj];

    if (z < 2) {
        ushortT* out = z ? kb : qb;
        #pragma unroll
        for (int i = 0; i < 4; ++i) {
            const int rr = row0 + (ty << 2) + i;
            ushort4 pk;
            pk.x = f2bf(c[i][0] + bvv[0]); pk.y = f2bf(c[i][1] + bvv[1]);
            pk.z = f2bf(c[i][2] + bvv[2]); pk.w = f2bf(c[i][3] + bvv[3]);
            *(ushort4*)(out + (size_t)rr * 256 + col0 + (tx << 2)) = pk;
        }
    } else {
        const int bb = row0 >> 9;                 // batch (64-row tile within one b)
        const int ntok = (row0 & 511) + (ty << 2);
        #pragma unroll
        for (int jj = 0; jj < 4; ++jj) {
            const int cc = col0 + (tx << 2) + jj;
            const int hh = cc >> 5, dd_ = cc & 31;
            ushort4 pk;
            pk.x = f2bf(c[0][jj] + bvv[jj]); pk.y = f2bf(c[1][jj] + bvv[jj]);
            pk.z = f2bf(c[2][jj] + bvv[jj]); pk.w = f2bf(c[3][jj] + bvv[jj]);
            *(ushort4*)(vbT + ((size_t)((bb * 8 + hh) * 32 + dd_)) * 512 + ntok) = pk;
        }
    }
}

// ---------------------------------------------------------------------------
// bcomb[j] = bs1[j] + sum_r bo[r&255] * Ws1[r][j]
// ---------------------------------------------------------------------------
__global__ void bcomb_k(const float* __restrict__ bo, const float* __restrict__ Ws1,
                        const float* __restrict__ bs1, float* __restrict__ bcomb)
{
    const int jj = threadIdx.x;
    const int r0 = blockIdx.x * 64;
    float acc = (blockIdx.x == 0) ? bs1[jj] : 0.f;
    for (int r = r0; r < r0 + 64; ++r)
        acc = fmaf(bo[r & 255], Ws1[(size_t)r * 256 + jj], acc);
    atomicAdd(&bcomb[jj], acc);
}

// ---------------------------------------------------------------------------
// MFMA flash attention, 3 scales. Block = (b,h) x 64 q rows; 4 waves x 16 q rows.
// C-layout (q=4Q+r, col=n); A-layout (q=n, k=8Q+j). S transposed once through LDS
// packed as (bf16 score | 3-bit scale code); P computed in A-layout, PV via mfma
// with V^T-staged B-frags. All LDS layouts padded to <=2-way bank aliasing (free).
// ---------------------------------------------------------------------------
__global__ __launch_bounds__(256, 2) void attn_k(
    const ushortT* __restrict__ qb, const ushortT* __restrict__ kb,
    const ushortT* __restrict__ vbT,
    const float* __restrict__ dist, const int* __restrict__ mask,
    const float* __restrict__ cw1, const float* __restrict__ cb1,
    const float* __restrict__ cw2, const float* __restrict__ cb2,
    float* __restrict__ OB)
{
    const int bh = blockIdx.x, b = bh >> 3, h = bh & 7;
    const int q0 = blockIdx.y * 64;
    const int t = threadIdx.x, w = t >> 6, lane = t & 63;
    const int Q = lane >> 4, n = lane & 15;

    __shared__ __align__(16) ushortT Ks[64][40];
    __shared__ __align__(16) ushortT Vt[32][72];
    __shared__ __align__(16) uintT Sx[4][16][68];
    __shared__ float Mx[4][3][16];
    __shared__ float Lx[4][3][16];

    float w1[8], b1[8], w2[8];
    #pragma unroll
    for (int i = 0; i < 8; ++i) { w1[i] = cw1[i]; b1[i] = cb1[i]; w2[i] = cw2[h * 8 + i]; }
    const float c2b = cb2[h];
    const float invs = 0.17677669529663687f;   // 1/sqrt(32)

    // Q A-fragment: lane (m=n, quad Q) holds Q[q0+w*16+n][Q*8 .. Q*8+7]
    short8 aq = *(const short8*)(qb + ((size_t)(b * 512 + q0 + w * 16 + n)) * 256 + h * 32 + Q * 8);

    const floatx4 zero4 = {0.f, 0.f, 0.f, 0.f};
    floatx4 acc[3][2];
    #pragma unroll
    for (int s = 0; s < 3; ++s) { acc[s][0] = zero4; acc[s][1] = zero4; }
    float mrow[3][4];
    #pragma unroll
    for (int s = 0; s < 3; ++s)
        #pragma unroll
        for (int r = 0; r < 4; ++r) mrow[s][r] = -3e38f;
    float mprevA[3] = {-3e38f, -3e38f, -3e38f};
    float lsum[3] = {0.f, 0.f, 0.f};

    for (int kc = 0; kc < 8; ++kc) {
        const int kk0 = kc * 64;
        __syncthreads();
        {   // stage K rows + V^T rows (bf16)
            const int row = t >> 2, cg = t & 3;
            *(short8*)&Ks[row][cg * 8] =
                *(const short8*)(kb + ((size_t)(b * 512 + kk0 + row)) * 256 + h * 32 + cg * 8);
            const int dr = t >> 3, seg = t & 7;
            *(short8*)&Vt[dr][seg * 8] =
                *(const short8*)(vbT + ((size_t)(bh * 32 + dr)) * 512 + kk0 + seg * 8);
        }
        __syncthreads();

        // ---- QK^T: S[q=4Q+r][col=cg*16+n] ----
        floatx4 s4[4];
        #pragma unroll
        for (int cg = 0; cg < 4; ++cg) {
            short8 kf = *(const short8*)&Ks[cg * 16 + n][Q * 8];
            s4[cg] = __builtin_amdgcn_mfma_f32_16x16x32_bf16(aq, kf, zero4, 0, 0, 0);
        }

        // ---- scale by f_h(d), mask codes, chunk row-max (C-layout) ----
        float sval[16]; uintT scode[16];
        float cm[3][4];
        #pragma unroll
        for (int s = 0; s < 3; ++s)
            #pragma unroll
            for (int r = 0; r < 4; ++r) cm[s][r] = -3e38f;
        #pragma unroll
        for (int cg = 0; cg < 4; ++cg) {
            #pragma unroll
            for (int r = 0; r < 4; ++r) {
                const int grow = q0 + w * 16 + 4 * Q + r;
                const int gcol = kk0 + cg * 16 + n;
                const size_t off = ((size_t)(b * 512 + grow)) * 512 + gcol;
                const float d = dist[off];
                const int mk = mask[off];
                float f = c2b;
                #pragma unroll
                for (int u = 0; u < 8; ++u)
                    f = fmaf(w2[u], fmaxf(fmaf(d, w1[u], b1[u]), 0.f), f);
                const float s = s4[cg][r] * invs * f;
                const bool force = (grow == 0) || (gcol == 0);
                const bool keep = (mk != 0);
                const uintT code = (keep && (force || d < 0.3f) ? 1u : 0u)
                                 | (keep && (force || d < 0.7f) ? 2u : 0u)
                                 | (keep ? 4u : 0u);
                sval[cg * 4 + r] = s;
                scode[cg * 4 + r] = code;
                if (code & 1u) cm[0][r] = fmaxf(cm[0][r], s);
                if (code & 2u) cm[1][r] = fmaxf(cm[1][r], s);
                if (code & 4u) cm[2][r] = fmaxf(cm[2][r], s);
            }
        }

        // ---- online max update + acc rescale (C-layout rows) ----
        #pragma unroll
        for (int s = 0; s < 3; ++s) {
            #pragma unroll
            for (int r = 0; r < 4; ++r) {
                float c = cm[s][r];
                c = fmaxf(c, __shfl_xor(c, 1));
                c = fmaxf(c, __shfl_xor(c, 2));
                c = fmaxf(c, __shfl_xor(c, 4));
                c = fmaxf(c, __shfl_xor(c, 8));
                const float mnew = fmaxf(mrow[s][r], c);
                const float alpha = __expf(mrow[s][r] - mnew);
                mrow[s][r] = mnew;
                acc[s][0][r] *= alpha;
                acc[s][1][r] *= alpha;
                if (n == 0) Mx[w][s][4 * Q + r] = mnew;
            }
        }

        // ---- write S (bf16 | code) transposed to per-wave LDS ----
        #pragma unroll
        for (int cg = 0; cg < 4; ++cg) {
            #pragma unroll
            for (int r = 0; r < 4; ++r) {
                const uintT u = __float_as_uint(sval[cg * 4 + r]);
                const uintT sb = (u + 0x7fffu + ((u >> 16) & 1u)) & 0xffff0000u;
                Sx[w][4 * Q + r][cg * 16 + n] = sb | scode[cg * 4 + r];
            }
        }

        // ---- A-layout: exp -> P frags, partial l (lane q = n, k = kb*32+Q*8+j) ----
        float mnew3[3], alphaA[3];
        #pragma unroll
        for (int s = 0; s < 3; ++s) {
            mnew3[s] = Mx[w][s][n];
            alphaA[s] = __expf(mprevA[s] - mnew3[s]);
            mprevA[s] = mnew3[s];
        }
        short8 pfrag[3][2];
        float lnew[3] = {0.f, 0.f, 0.f};
        #pragma unroll
        for (int kb2 = 0; kb2 < 2; ++kb2) {
            const uintT* sp = &Sx[w][n][kb2 * 32 + Q * 8];
            const uint4 xa = *(const uint4*)sp;
            const uint4 xb = *(const uint4*)(sp + 4);
            const uintT xs[8] = {xa.x, xa.y, xa.z, xa.w, xb.x, xb.y, xb.z, xb.w};
            uintT pk[3][4] = {};
            #pragma unroll
            for (int j = 0; j < 8; ++j) {
                const float sj = __uint_as_float(xs[j] & 0xffff0000u);
                const uintT cj = xs[j] & 7u;
                #pragma unroll
                for (int s = 0; s < 3; ++s) {
                    const float p = ((cj >> s) & 1u) ? __expf(sj - mnew3[s]) : 0.f;
                    lnew[s] += p;
                    pk[s][j >> 1] |= f2bf_u(p) << ((j & 1) * 16);
                }
            }
            #pragma unroll
            for (int s = 0; s < 3; ++s) {
                union { uint4 u; short8 v; } cv;
                cv.u = make_uint4(pk[s][0], pk[s][1], pk[s][2], pk[s][3]);
                pfrag[s][kb2] = cv.v;
            }
        }
        #pragma unroll
        for (int s = 0; s < 3; ++s) lsum[s] = lsum[s] * alphaA[s] + lnew[s];

        // ---- P @ V via mfma (B-frag from V^T staging) ----
        #pragma unroll
        for (int kb2 = 0; kb2 < 2; ++kb2) {
            #pragma unroll
            for (int nh = 0; nh < 2; ++nh) {
                short8 vf = *(const short8*)&Vt[nh * 16 + n][kb2 * 32 + Q * 8];
                #pragma unroll
                for (int s = 0; s < 3; ++s)
                    acc[s][nh] = __builtin_amdgcn_mfma_f32_16x16x32_bf16(
                        pfrag[s][kb2], vf, acc[s][nh], 0, 0, 0);
            }
        }
    }

    // ---- epilogue: reduce l across quads, normalize, write OB ----
    #pragma unroll
    for (int s = 0; s < 3; ++s) {
        float lv = lsum[s];
        lv += __shfl_xor(lv, 16);
        lv += __shfl_xor(lv, 32);
        if (Q == 0) Lx[w][s][n] = 1.0f / lv;
    }
    #pragma unroll
    for (int s = 0; s < 3; ++s) {
        #pragma unroll
        for (int r = 0; r < 4; ++r) {
            const float li = Lx[w][s][4 * Q + r];
            const int grow = q0 + w * 16 + 4 * Q + r;
            float* op = OB + (size_t)(b * 512 + grow) * 768 + s * 256 + h * 32 + n;
            op[0]  = acc[s][0][r] * li;
            op[16] = acc[s][1][r] * li;
        }
    }
}

// ---------------------------------------------------------------------------
extern "C" void kernel_launch(void* const* d_in, const int* in_sizes, int n_in,
                              void* d_out, int out_size, void* d_ws, size_t ws_size,
                              hipStream_t stream)
{
    const float* query = (const float*)d_in[0];
    const float* key   = (const float*)d_in[1];
    const float* value = (const float*)d_in[2];
    const float* dist  = (const float*)d_in[3];
    const int*   mask  = (const int*)d_in[4];
    const float* Wq = (const float*)d_in[5];  const float* bq = (const float*)d_in[6];
    const float* Wk = (const float*)d_in[7];  const float* bk = (const float*)d_in[8];
    const float* Wv = (const float*)d_in[9];  const float* bv = (const float*)d_in[10];
    const float* Wo = (const float*)d_in[11]; const float* bo = (const float*)d_in[12];
    const float* cw1 = (const float*)d_in[13]; const float* cb1 = (const float*)d_in[14];
    const float* cw2 = (const float*)d_in[15]; const float* cb2 = (const float*)d_in[16];
    const float* Ws1 = (const float*)d_in[17]; const float* bs1 = (const float*)d_in[18];
    const float* Ws2 = (const float*)d_in[19]; const float* bs2 = (const float*)d_in[20];

    ushortT* qb  = (ushortT*)d_ws;          // 4096x256 bf16
    ushortT* kb  = qb + 1048576;            // 4096x256 bf16
    ushortT* vbT = kb + 1048576;            // 64x32x512 bf16 (per (b,h), transposed)
    float* OB    = (float*)(vbT + 1048576); // 4096x768 fp32
    float* h1    = OB + 3145728;            // 4096x256
    float* Wbig  = h1 + 1048576;            // 768x256 = Wo @ Ws1_s stacked
    float* bcomb = Wbig + 196608;           // 256

    hipMemsetAsync(bcomb, 0, 256 * sizeof(float), stream);
    bcomb_k<<<dim3(12), dim3(256), 0, stream>>>(bo, Ws1, bs1, bcomb);

    qkv_gemm_k<<<dim3(64, 4, 3), 256, 0, stream>>>(query, key, value,
                                                   Wq, bq, Wk, bk, Wv, bv,
                                                   qb, kb, vbT);

    gemm_k<0, 0><<<dim3(4, 4, 3), 256, 0, stream>>>(Wo, Ws1, nullptr, Wbig,
                                                    256, 256, 256, 65536, 65536);

    attn_k<<<dim3(64, 8), 256, 0, stream>>>(qb, kb, vbT, dist, mask,
                                            cw1, cb1, cw2, cb2, OB);

    gemm_k<1, 1><<<dim3(64, 4, 1), 256, 0, stream>>>(OB, Wbig, bcomb, h1,
                                                     4096, 256, 768, 0, 0);
    gemm_k<0, 1><<<dim3(64, 4, 1), 256, 0, stream>>>(h1, Ws2, bs2, (float*)d_out,
                                                     4096, 256, 256, 0, 0);
}

// Round 3
// 193.154 us; speedup vs baseline: 1.8475x; 1.3994x over previous
//
#include <hip/hip_runtime.h>
#include <math.h>

typedef _Float16 h16;
typedef __attribute__((ext_vector_type(8))) _Float16 h16x8;
typedef __attribute__((ext_vector_type(4))) float f32x4;
typedef unsigned long long u64t;
typedef unsigned int u32t;
typedef unsigned short u16t;
typedef unsigned char u8t;

// ---------------------------------------------------------------------------
// bcomb[j] = bs1[j] + sum_{r=0..767} bo[r&255] * Ws1[r][j]   (bcomb pre-zeroed)
// ---------------------------------------------------------------------------
__global__ void bcomb_k(const float* __restrict__ bo, const float* __restrict__ Ws1,
                        const float* __restrict__ bs1, float* __restrict__ bcomb)
{
    const int jj = threadIdx.x;            // 256
    const int r0 = blockIdx.x * 64;        // grid 12
    float acc = (blockIdx.x == 0) ? bs1[jj] : 0.f;
    for (int r = r0; r < r0 + 64; ++r)
        acc = fmaf(bo[r & 255], Ws1[(size_t)r * 256 + jj], acc);
    atomicAdd(&bcomb[jj], acc);
}

// ---------------------------------------------------------------------------
// Transpose 256x256 f32 -> f16, z = 0..6: Wq, Wk, Wv, Ws2, Ws1_0, Ws1_1, Ws1_2
// ---------------------------------------------------------------------------
__global__ __launch_bounds__(256) void transpose_k(
    const float* __restrict__ Wq, const float* __restrict__ Wk,
    const float* __restrict__ Wv, const float* __restrict__ Ws2,
    const float* __restrict__ Ws1, h16* __restrict__ WT)
{
    const int z = blockIdx.z;
    const float* in = (z == 0) ? Wq : (z == 1) ? Wk : (z == 2) ? Wv :
                      (z == 3) ? Ws2 : (Ws1 + (size_t)(z - 4) * 65536);
    h16* out = WT + (size_t)z * 65536;
    __shared__ float T[32][33];
    const int t = threadIdx.x, tx = t & 31, ty = t >> 5;
    const int r0 = blockIdx.x * 32, c0 = blockIdx.y * 32;
    #pragma unroll
    for (int i = 0; i < 4; ++i) {
        const int row = ty + i * 8;
        T[row][tx] = in[(size_t)(r0 + row) * 256 + c0 + tx];
    }
    __syncthreads();
    #pragma unroll
    for (int i = 0; i < 4; ++i) {
        const int row = ty + i * 8;
        out[(size_t)(c0 + row) * 256 + r0 + tx] = (h16)T[tx][row];
    }
}

// ---------------------------------------------------------------------------
// Generic f16 MFMA GEMM: C = A(MxK) @ Bt^T (+bias). Bt is [N][K] f16.
// 64x64 tile, 4 waves (wave w: rows w*16..+15), k-step 32.
// MODE: 0 = f32 row-major (+bias), 2 = f16 row-major relu(+bias),
//       4 = f16 transposed: out[col*ldt + z*M + row] (no bias)   [WbigT]
// ---------------------------------------------------------------------------
template<int A_F32, int MODE>
__global__ __launch_bounds__(256) void hgemm_k(
    const void* __restrict__ Av, const h16* __restrict__ Bt0,
    const float* __restrict__ bias, void* __restrict__ outv,
    int M, int Nn, int K, long btz, int ldt)
{
    const h16* Bt = Bt0 + (size_t)blockIdx.z * btz;
    __shared__ __align__(16) h16 As[64][40];
    __shared__ __align__(16) h16 Bs[64][40];
    const int t = threadIdx.x, w = t >> 6, lane = t & 63;
    const int Q = lane >> 4, n = lane & 15;
    const int row0 = blockIdx.x * 64, col0 = blockIdx.y * 64;
    const int sr = t >> 2, sc = (t & 3) * 8;
    f32x4 acc[4];
    #pragma unroll
    for (int c = 0; c < 4; ++c) acc[c] = (f32x4){0.f, 0.f, 0.f, 0.f};

    for (int k0 = 0; k0 < K; k0 += 32) {
        __syncthreads();
        if (A_F32) {
            const float* ap = (const float*)Av + (size_t)(row0 + sr) * K + k0 + sc;
            float4 f0 = *(const float4*)ap;
            float4 f1 = *(const float4*)(ap + 4);
            h16x8 hv;
            hv[0] = (h16)f0.x; hv[1] = (h16)f0.y; hv[2] = (h16)f0.z; hv[3] = (h16)f0.w;
            hv[4] = (h16)f1.x; hv[5] = (h16)f1.y; hv[6] = (h16)f1.z; hv[7] = (h16)f1.w;
            *(h16x8*)&As[sr][sc] = hv;
        } else {
            *(h16x8*)&As[sr][sc] =
                *(const h16x8*)((const h16*)Av + (size_t)(row0 + sr) * K + k0 + sc);
        }
        *(h16x8*)&Bs[sr][sc] = *(const h16x8*)(Bt + (size_t)(col0 + sr) * K + k0 + sc);
        __syncthreads();
        h16x8 af = *(const h16x8*)&As[w * 16 + n][Q * 8];
        #pragma unroll
        for (int c = 0; c < 4; ++c) {
            h16x8 bf = *(const h16x8*)&Bs[c * 16 + n][Q * 8];
            acc[c] = __builtin_amdgcn_mfma_f32_16x16x32_f16(af, bf, acc[c], 0, 0, 0);
        }
    }

    float bvv[4] = {0.f, 0.f, 0.f, 0.f};
    if (MODE != 4) {
        #pragma unroll
        for (int c = 0; c < 4; ++c) bvv[c] = bias[col0 + c * 16 + n];
    }
    #pragma unroll
    for (int c = 0; c < 4; ++c) {
        #pragma unroll
        for (int r = 0; r < 4; ++r) {
            const int row = row0 + w * 16 + 4 * Q + r;
            const int col = col0 + c * 16 + n;
            if (MODE == 0) {
                ((float*)outv)[(size_t)row * Nn + col] = acc[c][r] + bvv[c];
            } else if (MODE == 2) {
                ((h16*)outv)[(size_t)row * Nn + col] = (h16)fmaxf(acc[c][r] + bvv[c], 0.f);
            } else {
                ((h16*)outv)[(size_t)col * ldt + (int)blockIdx.z * M + row] = (h16)acc[c][r];
            }
        }
    }
}

// ---------------------------------------------------------------------------
// QKV projection via MFMA, z = 0:Q, 1:K, 2:V. M=4096, N=256, K=256.
// Q/K -> f16 row-major; V -> f16 transposed per (b,h): vbT[(b*8+h)*32+d][tok].
// ---------------------------------------------------------------------------
__global__ __launch_bounds__(256) void qkv_hgemm_k(
    const float* __restrict__ Xq, const float* __restrict__ Xk,
    const float* __restrict__ Xv, const h16* __restrict__ WT,
    const float* __restrict__ bq, const float* __restrict__ bk,
    const float* __restrict__ bv,
    h16* __restrict__ qb, h16* __restrict__ kb, h16* __restrict__ vbT)
{
    const int z = blockIdx.z;
    const float* A    = (z == 0) ? Xq : (z == 1) ? Xk : Xv;
    const h16*   Bt   = WT + (size_t)z * 65536;
    const float* bias = (z == 0) ? bq : (z == 1) ? bk : bv;

    __shared__ __align__(16) h16 As[64][40];
    __shared__ __align__(16) h16 Bs[64][40];
    const int t = threadIdx.x, w = t >> 6, lane = t & 63;
    const int Q = lane >> 4, n = lane & 15;
    const int row0 = blockIdx.x * 64, col0 = blockIdx.y * 64;
    const int sr = t >> 2, sc = (t & 3) * 8;
    f32x4 acc[4];
    #pragma unroll
    for (int c = 0; c < 4; ++c) acc[c] = (f32x4){0.f, 0.f, 0.f, 0.f};

    for (int k0 = 0; k0 < 256; k0 += 32) {
        __syncthreads();
        {
            const float* ap = A + (size_t)(row0 + sr) * 256 + k0 + sc;
            float4 f0 = *(const float4*)ap;
            float4 f1 = *(const float4*)(ap + 4);
            h16x8 hv;
            hv[0] = (h16)f0.x; hv[1] = (h16)f0.y; hv[2] = (h16)f0.z; hv[3] = (h16)f0.w;
            hv[4] = (h16)f1.x; hv[5] = (h16)f1.y; hv[6] = (h16)f1.z; hv[7] = (h16)f1.w;
            *(h16x8*)&As[sr][sc] = hv;
            *(h16x8*)&Bs[sr][sc] = *(const h16x8*)(Bt + (size_t)(col0 + sr) * 256 + k0 + sc);
        }
        __syncthreads();
        h16x8 af = *(const h16x8*)&As[w * 16 + n][Q * 8];
        #pragma unroll
        for (int c = 0; c < 4; ++c) {
            h16x8 bf = *(const h16x8*)&Bs[c * 16 + n][Q * 8];
            acc[c] = __builtin_amdgcn_mfma_f32_16x16x32_f16(af, bf, acc[c], 0, 0, 0);
        }
    }

    float bvv[4];
    #pragma unroll
    for (int c = 0; c < 4; ++c) bvv[c] = bias[col0 + c * 16 + n];

    if (z < 2) {
        h16* out = z ? kb : qb;
        #pragma unroll
        for (int c = 0; c < 4; ++c)
            #pragma unroll
            for (int r = 0; r < 4; ++r)
                out[(size_t)(row0 + w * 16 + 4 * Q + r) * 256 + col0 + c * 16 + n] =
                    (h16)(acc[c][r] + bvv[c]);
    } else {
        const int bb = row0 >> 9;
        #pragma unroll
        for (int c = 0; c < 4; ++c)
            #pragma unroll
            for (int r = 0; r < 4; ++r) {
                const int m = row0 + w * 16 + 4 * Q + r;
                const int col = col0 + c * 16 + n;
                vbT[((size_t)(bb * 256 + col)) * 512 + (m & 511)] = (h16)(acc[c][r] + bvv[c]);
            }
    }
}

// ---------------------------------------------------------------------------
// MFMA flash attention, 3 scales sharing ONE online max (scale sets are nested).
// Block = (b, 16 q-rows) x 4 heads: 256 thr, wave w = head hg*4+w, 16q x 512k.
// dist/mask staged once per block; c1 channels (head-indep) in LDS; per-head
// dist-conv dot uses wave-uniform SGPRs. K/V frags read from global (L2-hot).
// S round-trips per-wave LDS (C-layout -> A-layout); P in f16, PV via MFMA.
// ---------------------------------------------------------------------------
__global__ __launch_bounds__(256, 4) void attn_k(
    const h16* __restrict__ qb, const h16* __restrict__ kb,
    const h16* __restrict__ vbT,
    const float* __restrict__ dist, const int* __restrict__ mask,
    const float* __restrict__ cw1, const float* __restrict__ cb1,
    const float* __restrict__ cw2, const float* __restrict__ cb2,
    h16* __restrict__ OB)
{
    const int bx = blockIdx.x, b = bx >> 5, q0 = (bx & 31) * 16;
    const int t = threadIdx.x, w = t >> 6, lane = t & 63;
    const int Q = lane >> 4, n = lane & 15;
    const int h = blockIdx.y * 4 + w;

    __shared__ __align__(16) h16 c1t[16][65][8];  // c1 channels per (q,k)
    __shared__ __align__(16) u8t Cd[16][72];      // 3-bit scale codes
    __shared__ __align__(16) h16 Sx[4][16][72];   // per-wave score transpose

    const float invs = 0.17677669529663687f;      // 1/sqrt(32)
    float w1[8], b1[8], w2w[8];
    #pragma unroll
    for (int u = 0; u < 8; ++u) {
        w1[u] = cw1[u]; b1[u] = cb1[u];
        w2w[u] = invs * cw2[h * 8 + u];
    }
    const float fb = invs * cb2[h];

    // Q A-fragment for this wave's 16 rows
    const h16x8 aq =
        *(const h16x8*)(qb + ((size_t)(b * 512 + q0 + n)) * 256 + h * 32 + Q * 8);

    const f32x4 z4 = {0.f, 0.f, 0.f, 0.f};
    f32x4 acc[3][2];
    #pragma unroll
    for (int s = 0; s < 3; ++s) { acc[s][0] = z4; acc[s][1] = z4; }
    float mprev = -3e38f;
    float lsum[3] = {0.f, 0.f, 0.f};

    const int scol = t & 63, srow0 = t >> 6;      // staging map: 4 rows/thread

    for (int kc = 0; kc < 8; ++kc) {
        const int kk0 = kc * 64;
        __syncthreads();
        // ---- stage dist-derived tiles (once per block) ----
        #pragma unroll
        for (int i = 0; i < 4; ++i) {
            const int row = srow0 + 4 * i;
            const size_t off = ((size_t)(b * 512 + q0 + row)) * 512 + kk0 + scol;
            const float d = dist[off];
            const int mk = mask[off];
            const bool fr = ((q0 + row) == 0) || ((kk0 + scol) == 0);
            const bool keep = (mk != 0);
            const u32t code = (keep && (fr || d < 0.3f) ? 1u : 0u)
                            | (keep && (fr || d < 0.7f) ? 2u : 0u)
                            | (keep ? 4u : 0u);
            Cd[row][scol] = (u8t)code;
            h16x8 ch;
            #pragma unroll
            for (int u = 0; u < 8; ++u)
                ch[u] = (h16)fmaxf(fmaf(d, w1[u], b1[u]), 0.f);
            *(h16x8*)&c1t[row][scol][0] = ch;
        }
        __syncthreads();

        // ---- QK^T (C-layout: row=4Q+r, col=cg*16+n) ----
        f32x4 s4[4];
        #pragma unroll
        for (int cg = 0; cg < 4; ++cg) {
            h16x8 kf = *(const h16x8*)(
                kb + ((size_t)(b * 512 + kk0 + cg * 16 + n)) * 256 + h * 32 + Q * 8);
            s4[cg] = __builtin_amdgcn_mfma_f32_16x16x32_f16(aq, kf, z4, 0, 0, 0);
        }
        // ---- apply f_h(d), write S transposed to per-wave LDS ----
        #pragma unroll
        for (int cg = 0; cg < 4; ++cg) {
            #pragma unroll
            for (int r = 0; r < 4; ++r) {
                h16x8 ch = *(const h16x8*)&c1t[4 * Q + r][cg * 16 + n][0];
                float f = fb;
                #pragma unroll
                for (int u = 0; u < 8; ++u)
                    f = fmaf((float)ch[u], w2w[u], f);
                Sx[w][4 * Q + r][cg * 16 + n] = (h16)(s4[cg][r] * f);
            }
        }
        __builtin_amdgcn_wave_barrier();   // keep ds_write -> ds_read order

        // ---- A-layout (lane row = n, k = kb2*32 + Q*8 + j) ----
        float sv[16];
        u64t cd0 = *(const u64t*)&Cd[n][Q * 8];
        u64t cd1 = *(const u64t*)&Cd[n][32 + Q * 8];
        {
            h16x8 sh0 = *(const h16x8*)&Sx[w][n][Q * 8];
            h16x8 sh1 = *(const h16x8*)&Sx[w][n][32 + Q * 8];
            #pragma unroll
            for (int j = 0; j < 8; ++j) { sv[j] = (float)sh0[j]; sv[8 + j] = (float)sh1[j]; }
        }
        float cm = -3e38f;
        #pragma unroll
        for (int i = 0; i < 16; ++i) {
            const u32t cc = (u32t)((i < 8 ? cd0 : cd1) >> (8 * (i & 7))) & 7u;
            cm = fmaxf(cm, (cc & 4u) ? sv[i] : -3e38f);
        }
        cm = fmaxf(cm, __shfl_xor(cm, 16));
        cm = fmaxf(cm, __shfl_xor(cm, 32));
        const float mnew = fmaxf(mprev, cm);
        const float alphaA = __expf(mprev - mnew);
        mprev = mnew;

        // rescale acc (C-layout rows need row-wise alpha via shfl)
        #pragma unroll
        for (int r = 0; r < 4; ++r) {
            const float aR = __shfl(alphaA, 4 * Q + r);
            #pragma unroll
            for (int s = 0; s < 3; ++s) { acc[s][0][r] *= aR; acc[s][1][r] *= aR; }
        }

        // exp + per-scale P fragments (f16) + l partials
        h16x8 pf[3][2];
        float l0 = 0.f, l1 = 0.f, l2 = 0.f;
        #pragma unroll
        for (int i = 0; i < 16; ++i) {
            const u32t cc = (u32t)((i < 8 ? cd0 : cd1) >> (8 * (i & 7))) & 7u;
            const float e = __expf(sv[i] - mnew);
            const float p0 = (cc & 1u) ? e : 0.f;
            const float p1 = (cc & 2u) ? e : 0.f;
            const float p2 = (cc & 4u) ? e : 0.f;
            l0 += p0; l1 += p1; l2 += p2;
            pf[0][i >> 3][i & 7] = (h16)p0;
            pf[1][i >> 3][i & 7] = (h16)p1;
            pf[2][i >> 3][i & 7] = (h16)p2;
        }
        lsum[0] = lsum[0] * alphaA + l0;
        lsum[1] = lsum[1] * alphaA + l1;
        lsum[2] = lsum[2] * alphaA + l2;

        // ---- P @ V (B-frags straight from global vbT) ----
        #pragma unroll
        for (int kb2 = 0; kb2 < 2; ++kb2) {
            #pragma unroll
            for (int nh = 0; nh < 2; ++nh) {
                h16x8 vf = *(const h16x8*)(
                    vbT + ((size_t)((b * 8 + h) * 32 + nh * 16 + n)) * 512
                        + kk0 + kb2 * 32 + Q * 8);
                #pragma unroll
                for (int s = 0; s < 3; ++s)
                    acc[s][nh] = __builtin_amdgcn_mfma_f32_16x16x32_f16(
                        pf[s][kb2], vf, acc[s][nh], 0, 0, 0);
            }
        }
    }

    // ---- epilogue: full-row l via shfl, normalize, write OB (f16) ----
    float lrow[3];
    #pragma unroll
    for (int s = 0; s < 3; ++s) {
        float lv = lsum[s];
        lv += __shfl_xor(lv, 16);
        lv += __shfl_xor(lv, 32);
        lrow[s] = lv;
    }
    #pragma unroll
    for (int s = 0; s < 3; ++s) {
        #pragma unroll
        for (int r = 0; r < 4; ++r) {
            const float il = 1.0f / __shfl(lrow[s], 4 * Q + r);
            const size_t row = (size_t)(b * 512 + q0 + 4 * Q + r);
            h16* op = OB + row * 768 + s * 256 + h * 32 + n;
            op[0]  = (h16)(acc[s][0][r] * il);
            op[16] = (h16)(acc[s][1][r] * il);
        }
    }
}

// ---------------------------------------------------------------------------
extern "C" void kernel_launch(void* const* d_in, const int* in_sizes, int n_in,
                              void* d_out, int out_size, void* d_ws, size_t ws_size,
                              hipStream_t stream)
{
    const float* query = (const float*)d_in[0];
    const float* key   = (const float*)d_in[1];
    const float* value = (const float*)d_in[2];
    const float* dist  = (const float*)d_in[3];
    const int*   mask  = (const int*)d_in[4];
    const float* Wq = (const float*)d_in[5];  const float* bq = (const float*)d_in[6];
    const float* Wk = (const float*)d_in[7];  const float* bk = (const float*)d_in[8];
    const float* Wv = (const float*)d_in[9];  const float* bv = (const float*)d_in[10];
    const float* Wo = (const float*)d_in[11]; const float* bo = (const float*)d_in[12];
    const float* cw1 = (const float*)d_in[13]; const float* cb1 = (const float*)d_in[14];
    const float* cw2 = (const float*)d_in[15]; const float* cb2 = (const float*)d_in[16];
    const float* Ws1 = (const float*)d_in[17]; const float* bs1 = (const float*)d_in[18];
    const float* Ws2 = (const float*)d_in[19]; const float* bs2 = (const float*)d_in[20];

    h16* qb    = (h16*)d_ws;            // 4096x256
    h16* kb    = qb + 1048576;          // 4096x256
    h16* vbT   = kb + 1048576;          // 64x32 x 512
    h16* OB    = vbT + 1048576;         // 4096x768
    h16* h1    = OB + 3145728;          // 4096x256
    h16* WT    = h1 + 1048576;          // 7 x 256x256 (WqT,WkT,WvT,Ws2T,Ws1T_0..2)
    h16* WbigT = WT + 458752;           // 256 x 768
    float* bcomb = (float*)(WbigT + 196608);  // 256

    hipMemsetAsync(bcomb, 0, 256 * sizeof(float), stream);
    bcomb_k<<<dim3(12), dim3(256), 0, stream>>>(bo, Ws1, bs1, bcomb);

    transpose_k<<<dim3(8, 8, 7), 256, 0, stream>>>(Wq, Wk, Wv, Ws2, Ws1, WT);

    // WbigT[n][s*256+e] = (Wo @ Ws1_s)[e][n]
    hgemm_k<1, 4><<<dim3(4, 4, 3), 256, 0, stream>>>(
        Wo, WT + 4 * 65536, nullptr, WbigT, 256, 256, 256, 65536, 768);

    qkv_hgemm_k<<<dim3(64, 4, 3), 256, 0, stream>>>(
        query, key, value, WT, bq, bk, bv, qb, kb, vbT);

    attn_k<<<dim3(256, 2), 256, 0, stream>>>(
        qb, kb, vbT, dist, mask, cw1, cb1, cw2, cb2, OB);

    hgemm_k<0, 2><<<dim3(64, 4, 1), 256, 0, stream>>>(
        OB, WbigT, bcomb, h1, 4096, 256, 768, 0, 0);
    hgemm_k<0, 0><<<dim3(64, 4, 1), 256, 0, stream>>>(
        h1, WT + 3 * 65536, bs2, d_out, 4096, 256, 256, 0, 0);
}

// Round 4
// 187.027 us; speedup vs baseline: 1.9081x; 1.0328x over previous
//
#include <hip/hip_runtime.h>
#include <math.h>

typedef _Float16 h16;
typedef __attribute__((ext_vector_type(8))) _Float16 h16x8;
typedef __attribute__((ext_vector_type(4))) float f32x4;
typedef unsigned long long u64t;
typedef unsigned int u32t;
typedef unsigned char u8t;

// ---------------------------------------------------------------------------
// prep_k: blocks 0..447 transpose {Wq,Wk,Wv,Ws2,Ws1_0,Ws1_1,Ws1_2} f32->f16
// into WT[z] (WT[z][c][r] = W_z[r][c]); block 448 computes bcomb.
// ---------------------------------------------------------------------------
__global__ __launch_bounds__(256) void prep_k(
    const float* __restrict__ Wq, const float* __restrict__ Wk,
    const float* __restrict__ Wv, const float* __restrict__ Ws2,
    const float* __restrict__ Ws1, const float* __restrict__ bo,
    const float* __restrict__ bs1, h16* __restrict__ WT,
    float* __restrict__ bcomb)
{
    const int bid = blockIdx.x;
    __shared__ float T[32][33];
    if (bid < 448) {
        const int z = bid >> 6, idx = bid & 63;
        const float* in = (z == 0) ? Wq : (z == 1) ? Wk : (z == 2) ? Wv :
                          (z == 3) ? Ws2 : (Ws1 + (size_t)(z - 4) * 65536);
        h16* out = WT + (size_t)z * 65536;
        const int t = threadIdx.x, tx = t & 31, ty = t >> 5;
        const int r0 = (idx >> 3) * 32, c0 = (idx & 7) * 32;
        #pragma unroll
        for (int i = 0; i < 4; ++i)
            T[ty + i * 8][tx] = in[(size_t)(r0 + ty + i * 8) * 256 + c0 + tx];
        __syncthreads();
        #pragma unroll
        for (int i = 0; i < 4; ++i)
            out[(size_t)(c0 + ty + i * 8) * 256 + r0 + tx] = (h16)T[tx][ty + i * 8];
    } else {
        const int j = threadIdx.x;
        float acc = bs1[j];
        for (int r = 0; r < 768; ++r)
            acc = fmaf(bo[r & 255], Ws1[(size_t)r * 256 + j], acc);
        bcomb[j] = acc;
    }
}

// ---------------------------------------------------------------------------
// qkvw_k: fused QKV projections (768 blocks) + Wbig = Wo @ Ws1_s (48 blocks).
// Double-buffered LDS, single barrier per k-iter. A is f32 (cvt on stage),
// Bt is pre-transposed f16 [N][K]. 64x64 tile, K=256, 8 iters.
// ---------------------------------------------------------------------------
__global__ __launch_bounds__(256) void qkvw_k(
    const float* __restrict__ Xq, const float* __restrict__ Xk,
    const float* __restrict__ Xv, const float* __restrict__ Wo,
    const h16* __restrict__ WT,
    const float* __restrict__ bq, const float* __restrict__ bk,
    const float* __restrict__ bv,
    h16* __restrict__ qb, h16* __restrict__ kb, h16* __restrict__ vbT,
    h16* __restrict__ WbigT)
{
    const int bid = blockIdx.x;
    const float* A; const h16* Bt; const float* bias = nullptr;
    int mode, row0, col0, sgm = 0;
    if (bid < 768) {
        const int z = bid >> 8, r = bid & 255;
        row0 = (r & 63) * 64; col0 = (r >> 6) * 64;
        A = (z == 0) ? Xq : (z == 1) ? Xk : Xv;
        Bt = WT + (size_t)z * 65536;
        bias = (z == 0) ? bq : (z == 1) ? bk : bv;
        mode = z;
    } else {
        const int r = bid - 768;
        sgm = r >> 4; const int tt = r & 15;
        row0 = (tt >> 2) * 64; col0 = (tt & 3) * 64;
        A = Wo; Bt = WT + (size_t)(4 + sgm) * 65536; mode = 3;
    }

    __shared__ __align__(16) h16 As[2][64][40];
    __shared__ __align__(16) h16 Bs[2][64][40];
    const int t = threadIdx.x, w = t >> 6, lane = t & 63;
    const int Q = lane >> 4, n = lane & 15;
    const int sr = t >> 2, sc = (t & 3) * 8;

    auto ldA = [&](int k0) -> h16x8 {
        const float* ap = A + (size_t)(row0 + sr) * 256 + k0 + sc;
        float4 f0 = *(const float4*)ap;
        float4 f1 = *(const float4*)(ap + 4);
        h16x8 hv;
        hv[0] = (h16)f0.x; hv[1] = (h16)f0.y; hv[2] = (h16)f0.z; hv[3] = (h16)f0.w;
        hv[4] = (h16)f1.x; hv[5] = (h16)f1.y; hv[6] = (h16)f1.z; hv[7] = (h16)f1.w;
        return hv;
    };
    auto ldB = [&](int k0) -> h16x8 {
        return *(const h16x8*)(Bt + (size_t)(col0 + sr) * 256 + k0 + sc);
    };

    {
        h16x8 a0 = ldA(0), b0 = ldB(0);
        *(h16x8*)&As[0][sr][sc] = a0;
        *(h16x8*)&Bs[0][sr][sc] = b0;
    }
    __syncthreads();

    f32x4 acc4[4];
    #pragma unroll
    for (int c = 0; c < 4; ++c) acc4[c] = (f32x4){0.f, 0.f, 0.f, 0.f};

    for (int it = 0; it < 8; ++it) {
        const int cur = it & 1;
        h16x8 arN, brN;
        if (it < 7) { arN = ldA(32 * (it + 1)); brN = ldB(32 * (it + 1)); }
        h16x8 af = *(const h16x8*)&As[cur][w * 16 + n][Q * 8];
        #pragma unroll
        for (int cg = 0; cg < 4; ++cg) {
            h16x8 bf = *(const h16x8*)&Bs[cur][cg * 16 + n][Q * 8];
            acc4[cg] = __builtin_amdgcn_mfma_f32_16x16x32_f16(af, bf, acc4[cg], 0, 0, 0);
        }
        if (it < 7) {
            *(h16x8*)&As[cur ^ 1][sr][sc] = arN;
            *(h16x8*)&Bs[cur ^ 1][sr][sc] = brN;
        }
        __syncthreads();
    }

    if (mode < 2) {
        h16* out = mode ? kb : qb;
        #pragma unroll
        for (int cg = 0; cg < 4; ++cg) {
            const float bvv = bias[col0 + cg * 16 + n];
            #pragma unroll
            for (int r = 0; r < 4; ++r)
                out[(size_t)(row0 + w * 16 + 4 * Q + r) * 256 + col0 + cg * 16 + n] =
                    (h16)(acc4[cg][r] + bvv);
        }
    } else if (mode == 2) {
        const int bb = row0 >> 9;
        #pragma unroll
        for (int cg = 0; cg < 4; ++cg) {
            const float bvv = bias[col0 + cg * 16 + n];
            const int col = col0 + cg * 16 + n;
            #pragma unroll
            for (int r = 0; r < 4; ++r) {
                const int m = row0 + w * 16 + 4 * Q + r;
                vbT[((size_t)(bb * 256 + col)) * 512 + (m & 511)] = (h16)(acc4[cg][r] + bvv);
            }
        }
    } else {
        #pragma unroll
        for (int cg = 0; cg < 4; ++cg) {
            const int col = col0 + cg * 16 + n;
            #pragma unroll
            for (int r = 0; r < 4; ++r)
                WbigT[(size_t)col * 768 + sgm * 256 + row0 + w * 16 + 4 * Q + r] =
                    (h16)acc4[cg][r];
        }
    }
}

// ---------------------------------------------------------------------------
// hgemm32_k: 32x64 tile, 256 thr (4 waves: wave w -> rows (w&1)*16, cols
// (w>>1)*32), k-step 64, double-buffered single-barrier. Nn=256 fixed.
// OUT16RELU: 1 -> f16 out relu(acc+bias); 0 -> f32 out acc+bias.
// ---------------------------------------------------------------------------
template<int OUT16RELU>
__global__ __launch_bounds__(256) void hgemm32_k(
    const h16* __restrict__ A, const h16* __restrict__ Bt,
    const float* __restrict__ bias, void* __restrict__ outv, int K)
{
    __shared__ __align__(16) h16 As[2][32][72];
    __shared__ __align__(16) h16 Bs[2][64][72];
    const int t = threadIdx.x, w = t >> 6, lane = t & 63;
    const int Q = lane >> 4, n = lane & 15;
    const int row0 = blockIdx.x * 32, col0 = blockIdx.y * 64;
    const int r16 = (w & 1) * 16, c32 = (w >> 1) * 32;
    const int asr = t >> 3, asc = (t & 7) * 8;
    const int bsr = t >> 2, bsc = (t & 3) * 16;

    auto ldA = [&](int k0) -> h16x8 {
        return *(const h16x8*)(A + (size_t)(row0 + asr) * K + k0 + asc);
    };
    auto ldB0 = [&](int k0) -> h16x8 {
        return *(const h16x8*)(Bt + (size_t)(col0 + bsr) * K + k0 + bsc);
    };
    auto ldB1 = [&](int k0) -> h16x8 {
        return *(const h16x8*)(Bt + (size_t)(col0 + bsr) * K + k0 + bsc + 8);
    };

    {
        h16x8 a0 = ldA(0), b0 = ldB0(0), b1 = ldB1(0);
        *(h16x8*)&As[0][asr][asc] = a0;
        *(h16x8*)&Bs[0][bsr][bsc] = b0;
        *(h16x8*)&Bs[0][bsr][bsc + 8] = b1;
    }
    __syncthreads();

    f32x4 acc2[2];
    acc2[0] = (f32x4){0.f, 0.f, 0.f, 0.f};
    acc2[1] = (f32x4){0.f, 0.f, 0.f, 0.f};
    const int iters = K >> 6;

    for (int it = 0; it < iters; ++it) {
        const int cur = it & 1;
        h16x8 arN, brN0, brN1;
        if (it + 1 < iters) {
            arN = ldA(64 * (it + 1));
            brN0 = ldB0(64 * (it + 1));
            brN1 = ldB1(64 * (it + 1));
        }
        #pragma unroll
        for (int kh = 0; kh < 2; ++kh) {
            h16x8 af = *(const h16x8*)&As[cur][r16 + n][kh * 32 + Q * 8];
            #pragma unroll
            for (int cg = 0; cg < 2; ++cg) {
                h16x8 bf = *(const h16x8*)&Bs[cur][c32 + cg * 16 + n][kh * 32 + Q * 8];
                acc2[cg] = __builtin_amdgcn_mfma_f32_16x16x32_f16(af, bf, acc2[cg], 0, 0, 0);
            }
        }
        if (it + 1 < iters) {
            *(h16x8*)&As[cur ^ 1][asr][asc] = arN;
            *(h16x8*)&Bs[cur ^ 1][bsr][bsc] = brN0;
            *(h16x8*)&Bs[cur ^ 1][bsr][bsc + 8] = brN1;
        }
        __syncthreads();
    }

    #pragma unroll
    for (int cg = 0; cg < 2; ++cg) {
        const int col = col0 + c32 + cg * 16 + n;
        const float bv = bias[col];
        #pragma unroll
        for (int r = 0; r < 4; ++r) {
            const int row = row0 + r16 + 4 * Q + r;
            if (OUT16RELU)
                ((h16*)outv)[(size_t)row * 256 + col] = (h16)fmaxf(acc2[cg][r] + bv, 0.f);
            else
                ((float*)outv)[(size_t)row * 256 + col] = acc2[cg][r] + bv;
        }
    }
}

// ---------------------------------------------------------------------------
// MFMA flash attention, 3 nested scales sharing one online max.
// Block = (b, 16 q-rows) x head-group of 4; software-pipelined: dist/mask +
// K/V fragments prefetched to regs for chunk kc+1 during chunk kc; dist-
// derived LDS (per-head f, codes) double-buffered -> ONE barrier per chunk.
// ---------------------------------------------------------------------------
__global__ __launch_bounds__(256, 2) void attn_k(
    const h16* __restrict__ qb, const h16* __restrict__ kb,
    const h16* __restrict__ vbT,
    const float* __restrict__ dist, const int* __restrict__ mask,
    const float* __restrict__ cw1, const float* __restrict__ cb1,
    const float* __restrict__ cw2, const float* __restrict__ cb2,
    h16* __restrict__ OB)
{
    const int bx = blockIdx.x, b = bx >> 5, q0 = (bx & 31) * 16;
    const int hg = blockIdx.y;
    const int t = threadIdx.x, w = t >> 6, lane = t & 63;
    const int Q = lane >> 4, n = lane & 15;
    const int h = hg * 4 + w;

    __shared__ __align__(16) h16 Ft[2][4][16][68];  // [buf][head][qrow][kcol]
    __shared__ __align__(16) u8t Cd[2][16][72];     // [buf][qrow][kcol] codes
    __shared__ __align__(16) h16 Sx[4][16][72];     // per-wave S transpose

    const float invs = 0.17677669529663687f;        // 1/sqrt(32)
    float w1[8], b1[8];
    #pragma unroll
    for (int u = 0; u < 8; ++u) { w1[u] = cw1[u]; b1[u] = cb1[u]; }
    float w2a[4][8], fba[4];
    #pragma unroll
    for (int hh = 0; hh < 4; ++hh) {
        #pragma unroll
        for (int u = 0; u < 8; ++u) w2a[hh][u] = invs * cw2[(hg * 4 + hh) * 8 + u];
        fba[hh] = invs * cb2[hg * 4 + hh];
    }

    const h16x8 aq =
        *(const h16x8*)(qb + ((size_t)(b * 512 + q0 + n)) * 256 + h * 32 + Q * 8);

    const f32x4 z4 = {0.f, 0.f, 0.f, 0.f};
    f32x4 acc[3][2];
    #pragma unroll
    for (int s = 0; s < 3; ++s) { acc[s][0] = z4; acc[s][1] = z4; }
    float mprev = -3e38f;
    float lsum[3] = {0.f, 0.f, 0.f};

    const int scol = lane;   // staging: rows w+4i, col = lane

    auto stage = [&](int buf, int kkb, const float* dp, const int* mp) {
        #pragma unroll
        for (int i = 0; i < 4; ++i) {
            const int row = w + 4 * i;
            const float d = dp[i];
            const bool fr = ((q0 + row) == 0) || ((kkb + scol) == 0);
            const bool keep = (mp[i] != 0);
            const u32t code = (keep && (fr || d < 0.3f) ? 1u : 0u)
                            | (keep && (fr || d < 0.7f) ? 2u : 0u)
                            | (keep ? 4u : 0u);
            Cd[buf][row][scol] = (u8t)code;
            float ch[8];
            #pragma unroll
            for (int u = 0; u < 8; ++u) ch[u] = fmaxf(fmaf(d, w1[u], b1[u]), 0.f);
            #pragma unroll
            for (int hh = 0; hh < 4; ++hh) {
                float f = fba[hh];
                #pragma unroll
                for (int u = 0; u < 8; ++u) f = fmaf(ch[u], w2a[hh][u], f);
                Ft[buf][hh][row][scol] = (h16)f;
            }
        }
    };

    // ---- prologue: chunk 0 loads + stage ----
    float dv[4]; int mkv[4];
    #pragma unroll
    for (int i = 0; i < 4; ++i) {
        const size_t off = ((size_t)(b * 512 + q0 + w + 4 * i)) * 512 + scol;
        dv[i] = dist[off]; mkv[i] = mask[off];
    }
    h16x8 kf[4], vf[4];
    #pragma unroll
    for (int cg = 0; cg < 4; ++cg)
        kf[cg] = *(const h16x8*)(kb + ((size_t)(b * 512 + cg * 16 + n)) * 256 + h * 32 + Q * 8);
    #pragma unroll
    for (int nh = 0; nh < 2; ++nh)
        #pragma unroll
        for (int k2 = 0; k2 < 2; ++k2)
            vf[nh * 2 + k2] = *(const h16x8*)(
                vbT + ((size_t)((b * 8 + h) * 32 + nh * 16 + n)) * 512 + k2 * 32 + Q * 8);
    stage(0, 0, dv, mkv);
    __syncthreads();

    for (int kc = 0; kc < 8; ++kc) {
        const int cur = kc & 1, kk0 = kc * 64;

        // ---- prefetch chunk kc+1 into regs ----
        float dN[4]; int mkN[4]; h16x8 kfN[4], vfN[4];
        if (kc < 7) {
            const int kn = kk0 + 64;
            #pragma unroll
            for (int i = 0; i < 4; ++i) {
                const size_t off = ((size_t)(b * 512 + q0 + w + 4 * i)) * 512 + kn + scol;
                dN[i] = dist[off]; mkN[i] = mask[off];
            }
            #pragma unroll
            for (int cg = 0; cg < 4; ++cg)
                kfN[cg] = *(const h16x8*)(
                    kb + ((size_t)(b * 512 + kn + cg * 16 + n)) * 256 + h * 32 + Q * 8);
            #pragma unroll
            for (int nh = 0; nh < 2; ++nh)
                #pragma unroll
                for (int k2 = 0; k2 < 2; ++k2)
                    vfN[nh * 2 + k2] = *(const h16x8*)(
                        vbT + ((size_t)((b * 8 + h) * 32 + nh * 16 + n)) * 512
                            + kn + k2 * 32 + Q * 8);
        }

        // ---- QK^T ----
        f32x4 s4[4];
        #pragma unroll
        for (int cg = 0; cg < 4; ++cg)
            s4[cg] = __builtin_amdgcn_mfma_f32_16x16x32_f16(aq, kf[cg], z4, 0, 0, 0);

        // ---- apply f_h(d) from LDS, write S transposed ----
        #pragma unroll
        for (int cg = 0; cg < 4; ++cg)
            #pragma unroll
            for (int r = 0; r < 4; ++r) {
                const float f = (float)Ft[cur][w][4 * Q + r][cg * 16 + n];
                Sx[w][4 * Q + r][cg * 16 + n] = (h16)(s4[cg][r] * f);
            }
        __builtin_amdgcn_wave_barrier();

        // ---- A-layout consume: softmax ----
        const u64t cd0 = *(const u64t*)&Cd[cur][n][Q * 8];
        const u64t cd1 = *(const u64t*)&Cd[cur][n][32 + Q * 8];
        float sv[16];
        {
            h16x8 s0 = *(const h16x8*)&Sx[w][n][Q * 8];
            h16x8 s1 = *(const h16x8*)&Sx[w][n][32 + Q * 8];
            #pragma unroll
            for (int j = 0; j < 8; ++j) { sv[j] = (float)s0[j]; sv[8 + j] = (float)s1[j]; }
        }
        float cm = -3e38f;
        #pragma unroll
        for (int i = 0; i < 16; ++i) {
            const u32t cc = (u32t)((i < 8 ? cd0 : cd1) >> (8 * (i & 7))) & 7u;
            cm = fmaxf(cm, (cc & 4u) ? sv[i] : -3e38f);
        }
        cm = fmaxf(cm, __shfl_xor(cm, 16));
        cm = fmaxf(cm, __shfl_xor(cm, 32));
        const float mnew = fmaxf(mprev, cm);
        const float alphaA = __expf(mprev - mnew);
        mprev = mnew;

        #pragma unroll
        for (int r = 0; r < 4; ++r) {
            const float aR = __shfl(alphaA, 4 * Q + r);
            #pragma unroll
            for (int s = 0; s < 3; ++s) { acc[s][0][r] *= aR; acc[s][1][r] *= aR; }
        }

        h16x8 pf[3][2];
        float l0 = 0.f, l1 = 0.f, l2 = 0.f;
        #pragma unroll
        for (int i = 0; i < 16; ++i) {
            const u32t cc = (u32t)((i < 8 ? cd0 : cd1) >> (8 * (i & 7))) & 7u;
            const float e = __expf(sv[i] - mnew);
            const float p0 = (cc & 1u) ? e : 0.f;
            const float p1 = (cc & 2u) ? e : 0.f;
            const float p2 = (cc & 4u) ? e : 0.f;
            l0 += p0; l1 += p1; l2 += p2;
            pf[0][i >> 3][i & 7] = (h16)p0;
            pf[1][i >> 3][i & 7] = (h16)p1;
            pf[2][i >> 3][i & 7] = (h16)p2;
        }
        lsum[0] = lsum[0] * alphaA + l0;
        lsum[1] = lsum[1] * alphaA + l1;
        lsum[2] = lsum[2] * alphaA + l2;

        // ---- P @ V ----
        #pragma unroll
        for (int k2 = 0; k2 < 2; ++k2)
            #pragma unroll
            for (int nh = 0; nh < 2; ++nh)
                #pragma unroll
                for (int s = 0; s < 3; ++s)
                    acc[s][nh] = __builtin_amdgcn_mfma_f32_16x16x32_f16(
                        pf[s][k2], vf[nh * 2 + k2], acc[s][nh], 0, 0, 0);

        // ---- stage chunk kc+1, rotate regs ----
        if (kc < 7) {
            stage(cur ^ 1, kk0 + 64, dN, mkN);
            #pragma unroll
            for (int i = 0; i < 4; ++i) { kf[i] = kfN[i]; vf[i] = vfN[i]; dv[i] = dN[i]; mkv[i] = mkN[i]; }
        }
        __syncthreads();
    }

    // ---- epilogue ----
    float lrow[3];
    #pragma unroll
    for (int s = 0; s < 3; ++s) {
        float lv = lsum[s];
        lv += __shfl_xor(lv, 16);
        lv += __shfl_xor(lv, 32);
        lrow[s] = lv;
    }
    #pragma unroll
    for (int s = 0; s < 3; ++s) {
        #pragma unroll
        for (int r = 0; r < 4; ++r) {
            const float il = 1.0f / __shfl(lrow[s], 4 * Q + r);
            const size_t row = (size_t)(b * 512 + q0 + 4 * Q + r);
            h16* op = OB + row * 768 + s * 256 + h * 32 + n;
            op[0]  = (h16)(acc[s][0][r] * il);
            op[16] = (h16)(acc[s][1][r] * il);
        }
    }
}

// ---------------------------------------------------------------------------
extern "C" void kernel_launch(void* const* d_in, const int* in_sizes, int n_in,
                              void* d_out, int out_size, void* d_ws, size_t ws_size,
                              hipStream_t stream)
{
    const float* query = (const float*)d_in[0];
    const float* key   = (const float*)d_in[1];
    const float* value = (const float*)d_in[2];
    const float* dist  = (const float*)d_in[3];
    const int*   mask  = (const int*)d_in[4];
    const float* Wq = (const float*)d_in[5];  const float* bq = (const float*)d_in[6];
    const float* Wk = (const float*)d_in[7];  const float* bk = (const float*)d_in[8];
    const float* Wv = (const float*)d_in[9];  const float* bv = (const float*)d_in[10];
    const float* Wo = (const float*)d_in[11]; const float* bo = (const float*)d_in[12];
    const float* cw1 = (const float*)d_in[13]; const float* cb1 = (const float*)d_in[14];
    const float* cw2 = (const float*)d_in[15]; const float* cb2 = (const float*)d_in[16];
    const float* Ws1 = (const float*)d_in[17]; const float* bs1 = (const float*)d_in[18];
    const float* Ws2 = (const float*)d_in[19]; const float* bs2 = (const float*)d_in[20];

    h16* qb    = (h16*)d_ws;            // 4096x256
    h16* kb    = qb + 1048576;          // 4096x256
    h16* vbT   = kb + 1048576;          // 64x32 x 512
    h16* OB    = vbT + 1048576;         // 4096x768
    h16* h1    = OB + 3145728;          // 4096x256
    h16* WT    = h1 + 1048576;          // 7 x 256x256
    h16* WbigT = WT + 458752;           // 256 x 768
    float* bcomb = (float*)(WbigT + 196608);  // 256

    prep_k<<<dim3(449), 256, 0, stream>>>(Wq, Wk, Wv, Ws2, Ws1, bo, bs1, WT, bcomb);

    qkvw_k<<<dim3(816), 256, 0, stream>>>(query, key, value, Wo, WT,
                                          bq, bk, bv, qb, kb, vbT, WbigT);

    attn_k<<<dim3(256, 2), 256, 0, stream>>>(qb, kb, vbT, dist, mask,
                                             cw1, cb1, cw2, cb2, OB);

    hgemm32_k<1><<<dim3(128, 4), 256, 0, stream>>>(OB, WbigT, bcomb, h1, 768);
    hgemm32_k<0><<<dim3(128, 4), 256, 0, stream>>>(h1, WT + 3 * 65536, bs2, d_out, 256);
}